// Round 14
// baseline (262.459 us; speedup 1.0000x reference)
//
#include <hip/hip_runtime.h>
#include <hip/hip_bf16.h>

#define SEQ 4096
#define EMB 1024
#define NHD 16
#define HDD 64

using bf16 = __hip_bfloat16;
using bf16x8 = __attribute__((ext_vector_type(8))) short;
using f32x2  = __attribute__((ext_vector_type(2))) float;
using f32x4  = __attribute__((ext_vector_type(4))) float;
using f32x16 = __attribute__((ext_vector_type(16))) float;
using u32x4  = __attribute__((ext_vector_type(4))) unsigned int;
using u32x2  = __attribute__((ext_vector_type(2))) unsigned int;

#define MFMA16(a, b, c) __builtin_amdgcn_mfma_f32_16x16x32_bf16((a), (b), (c), 0, 0, 0)
#define MFMA32(a, b, c) __builtin_amdgcn_mfma_f32_32x32x16_bf16((a), (b), (c), 0, 0, 0)

// logit scale: 1/sqrt(64) * log2(e), folded into Q projection
#define QSCALE 0.1803368801111204f

__device__ __forceinline__ float b2f(bf16 b) { return __bfloat162float(b); }

__device__ __forceinline__ void gll16(const void* g, void* l) {
    __builtin_amdgcn_global_load_lds(
        (const __attribute__((address_space(1))) unsigned int*)g,
        (__attribute__((address_space(3))) unsigned int*)l, 16, 0, 0);
}

__device__ __forceinline__ unsigned pack_bf16x2(float a, float b) {
    __hip_bfloat162 p = __float22bfloat162_rn(make_float2(a, b));
    unsigned w;
    __builtin_memcpy(&w, &p, 4);
    return w;
}

// ---- VOP3P packed-f32 helpers (gfx950 has pk_add/pk_mul, NOT pk_max) ----
__device__ __forceinline__ f32x2 pk_add(f32x2 a, f32x2 b) {
    f32x2 d;
    asm("v_pk_add_f32 %0, %1, %2" : "=v"(d) : "v"(a), "v"(b));
    return d;
}
__device__ __forceinline__ f32x2 pk_mul(f32x2 a, f32x2 b) {
    f32x2 d;
    asm("v_pk_mul_f32 %0, %1, %2" : "=v"(d) : "v"(a), "v"(b));
    return d;
}

// cross-half (lane i <-> i+32) reduce via permlane32_swap mirror trick
__device__ __forceinline__ float xhalf_max(float x) {
    unsigned u;
    __builtin_memcpy(&u, &x, 4);
    u32x2 r = __builtin_amdgcn_permlane32_swap(u, u, false, false);
    unsigned u0 = r[0], u1 = r[1];
    float a, b;
    __builtin_memcpy(&a, &u0, 4);
    __builtin_memcpy(&b, &u1, 4);
    return fmaxf(a, b);
}
__device__ __forceinline__ float xhalf_sum(float x) {
    unsigned u;
    __builtin_memcpy(&u, &x, 4);
    u32x2 r = __builtin_amdgcn_permlane32_swap(u, u, false, false);
    unsigned u0 = r[0], u1 = r[1];
    float a, b;
    __builtin_memcpy(&a, &u0, 4);
    __builtin_memcpy(&b, &u1, 4);
    return a + b;
}

// ---------------- prep: W transpose+split (z<3) and x split (z==3) --------
__global__ void prep_kernel(const float* __restrict__ x,
                            const float* __restrict__ Wq, const float* __restrict__ Wk,
                            const float* __restrict__ Wv,
                            bf16* __restrict__ xh, bf16* __restrict__ xl,
                            bf16* __restrict__ thq, bf16* __restrict__ tlq,
                            bf16* __restrict__ thk, bf16* __restrict__ tlk,
                            bf16* __restrict__ thv) {
    __shared__ float tile[32][33];
    int tx = threadIdx.x, ty = threadIdx.y;
    if (blockIdx.z == 3) {
        // x split: 1024 blocks x 256 thr x 4 float4 = 4M floats
        int tid = (blockIdx.y * 32 + blockIdx.x) * 256 + ty * 32 + tx;
#pragma unroll
        for (int c = 0; c < 4; c++) {
            int i = tid * 4 + c;  // float4 index
            float4 v = ((const float4*)x)[i];
            float vv[4] = {v.x, v.y, v.z, v.w};
#pragma unroll
            for (int j = 0; j < 4; j++) {
                bf16 h = __float2bfloat16(vv[j]);
                xh[i * 4 + j] = h;
                xl[i * 4 + j] = __float2bfloat16(vv[j] - b2f(h));
            }
        }
        return;
    }
    const float* W;
    bf16 *wth, *wtl;
    if (blockIdx.z == 0) { W = Wq; wth = thq; wtl = tlq; }
    else if (blockIdx.z == 1) { W = Wk; wth = thk; wtl = tlk; }
    else { W = Wv; wth = thv; wtl = nullptr; }  // V: lo never consumed
    int n0 = blockIdx.x * 32, k0 = blockIdx.y * 32;
    for (int r = ty; r < 32; r += 8)
        tile[r][tx] = W[(k0 + r) * EMB + n0 + tx];
    __syncthreads();
    for (int r = ty; r < 32; r += 8) {
        float v = tile[tx][r];  // = W[k0+tx][n0+r]
        bf16 h = __float2bfloat16(v);
        wth[(n0 + r) * EMB + k0 + tx] = h;
        if (wtl != nullptr)
            wtl[(n0 + r) * EMB + k0 + tx] = __float2bfloat16(v - b2f(h));
    }
}

// ---------------- fused QKV projection GEMM ----------------
template <int NTERMS>
__device__ __forceinline__ void proj_loop(
    const bf16* __restrict__ Ah, const bf16* __restrict__ Al,
    const bf16* __restrict__ Bth, const bf16* __restrict__ Btl,
    bf16* lAh, bf16* lAl, bf16* lBh, bf16* lBl,
    int m0, int n0, int t, f32x4 (&acc)[4][4]) {
    const int wid = t >> 6, lane = t & 63, lr = lane & 15, lg = lane >> 4;
    const int wr = (wid >> 1) * 64, wc = (wid & 1) * 64;
    for (int k0 = 0; k0 < EMB; k0 += 32) {
#pragma unroll
        for (int c = t; c < 512; c += 256) {
            int row = c >> 2, slot = c & 3;
            *(uint4*)&lAh[row * 40 + slot * 8] =
                *(const uint4*)&Ah[(m0 + row) * EMB + k0 + slot * 8];
            *(uint4*)&lBh[row * 40 + slot * 8] =
                *(const uint4*)&Bth[(n0 + row) * EMB + k0 + slot * 8];
            if constexpr (NTERMS == 3) {
                *(uint4*)&lAl[row * 40 + slot * 8] =
                    *(const uint4*)&Al[(m0 + row) * EMB + k0 + slot * 8];
                *(uint4*)&lBl[row * 40 + slot * 8] =
                    *(const uint4*)&Btl[(n0 + row) * EMB + k0 + slot * 8];
            }
        }
        __syncthreads();
        bf16x8 fah[4], fbh[4], fal[4], fbl[4];
#pragma unroll
        for (int i = 0; i < 4; i++) {
            fah[i] = *(const bf16x8*)&lAh[(wr + i * 16 + lr) * 40 + lg * 8];
            fbh[i] = *(const bf16x8*)&lBh[(wc + i * 16 + lr) * 40 + lg * 8];
            if constexpr (NTERMS == 3) {
                fal[i] = *(const bf16x8*)&lAl[(wr + i * 16 + lr) * 40 + lg * 8];
                fbl[i] = *(const bf16x8*)&lBl[(wc + i * 16 + lr) * 40 + lg * 8];
            }
        }
#pragma unroll
        for (int i = 0; i < 4; i++)
#pragma unroll
            for (int j = 0; j < 4; j++) {
                acc[i][j] = MFMA16(fah[i], fbh[j], acc[i][j]);
                if constexpr (NTERMS == 3) {
                    acc[i][j] = MFMA16(fah[i], fbl[j], acc[i][j]);
                    acc[i][j] = MFMA16(fal[i], fbh[j], acc[i][j]);
                }
            }
        __syncthreads();
    }
}

// grid (24, 32): x covers 3*EMB columns (8 tiles each for Q,K,V), y covers SEQ rows
__global__ __launch_bounds__(256) void proj_qkv(
    const bf16* __restrict__ xh, const bf16* __restrict__ xl,
    const bf16* __restrict__ thq, const bf16* __restrict__ tlq,
    const bf16* __restrict__ thk, const bf16* __restrict__ tlk,
    const bf16* __restrict__ thv,
    bf16* __restrict__ qh, bf16* __restrict__ ql,
    bf16* __restrict__ kh, bf16* __restrict__ kl, bf16* __restrict__ vt) {
    __shared__ __align__(16) bf16 lAh[128 * 40];
    __shared__ __align__(16) bf16 lAl[128 * 40];
    __shared__ __align__(16) bf16 lBh[128 * 40];
    __shared__ __align__(16) bf16 lBl[128 * 40];
    const int t = threadIdx.x;
    const int m0 = blockIdx.y * 128;
    const int which = blockIdx.x >> 3;
    const int n0 = (blockIdx.x & 7) * 128;

    f32x4 acc[4][4];
#pragma unroll
    for (int i = 0; i < 4; i++)
#pragma unroll
        for (int j = 0; j < 4; j++) acc[i][j] = (f32x4){0.f, 0.f, 0.f, 0.f};

    if (which == 0)
        proj_loop<3>(xh, xl, thq, tlq, lAh, lAl, lBh, lBl, m0, n0, t, acc);
    else if (which == 1)
        proj_loop<3>(xh, xl, thk, tlk, lAh, lAl, lBh, lBl, m0, n0, t, acc);
    else
        proj_loop<1>(xh, xl, thv, nullptr, lAh, lAl, lBh, lBl, m0, n0, t, acc);

    const int wid = t >> 6, lane = t & 63, lr = lane & 15, lg = lane >> 4;
    const int wr = (wid >> 1) * 64, wc = (wid & 1) * 64;

    if (which == 2) {
        // V: write directly transposed vt[(h*64+d)*SEQ + m], 8B packed stores
#pragma unroll
        for (int i = 0; i < 4; i++)
#pragma unroll
            for (int j = 0; j < 4; j++) {
                int n = n0 + wc + j * 16 + lr;       // column in V = h*64 + d
                int m = m0 + wr + i * 16 + lg * 4;   // 4 consecutive seq rows
                uint2 w;
                w.x = pack_bf16x2(acc[i][j][0], acc[i][j][1]);
                w.y = pack_bf16x2(acc[i][j][2], acc[i][j][3]);
                *(uint2*)&vt[(size_t)n * SEQ + m] = w;
            }
    } else {
        float scale = (which == 0) ? QSCALE : 1.0f;
        bf16* Chi = (which == 0) ? qh : kh;
        bf16* Clo = (which == 0) ? ql : kl;
#pragma unroll
        for (int i = 0; i < 4; i++)
#pragma unroll
            for (int j = 0; j < 4; j++)
#pragma unroll
                for (int q = 0; q < 4; q++) {
                    float cv = acc[i][j][q] * scale;
                    int m = m0 + wr + i * 16 + lg * 4 + q;
                    int n = n0 + wc + j * 16 + lr;
                    bf16 hv = __float2bfloat16(cv);
                    Chi[m * EMB + n] = hv;
                    Clo[m * EMB + n] = __float2bfloat16(cv - b2f(hv));
                }
    }
}

// ---------------- fused flash attention v10: round-7 structure + VALU trims
// 8 waves, QBLK=256, KVBLK=64, dbuf K/V (48KB), grid 256 = 1 block/CU,
// XCD-swizzled, in-register P via cvt_pk+permlane32_swap, per-tile softmax
// ONCE per 64 keys. New vs r7: packed sub/rescale (v_pk_add/v_pk_mul),
// nested-fmax max tree (max3-fusable), permlane mirror cross-half reduces.
__global__ __launch_bounds__(512, 2) void attn_kernel(
    const bf16* __restrict__ qh, const bf16* __restrict__ ql,
    const bf16* __restrict__ kh, const bf16* __restrict__ kl,
    const bf16* __restrict__ vt, float* __restrict__ out) {
    __shared__ __align__(16) bf16 lKV[2][3][64 * 64];  // 48 KB
    const int t = threadIdx.x;
    // XCD-bijective swizzle (256 % 8 == 0): 32 consecutive swz per XCD = 2 heads
    const int swz = (blockIdx.x & 7) * 32 + (blockIdx.x >> 3);
    const int h = swz >> 4;
    const int q0 = (swz & 15) * 256;
    const int wid = t >> 6, lane = t & 63;
    const int qq = lane & 31, hi = lane >> 5;
    const int qrow = q0 + wid * 32 + qq;

    // Q fragments (B-operand): col q = lane&31, k(d) = ds*16 + hi*8 + i
    bf16x8 fqh[4], fql[4];
    {
        const bf16* qbh = qh + (size_t)qrow * EMB + h * HDD + hi * 8;
        const bf16* qbl = ql + (size_t)qrow * EMB + h * HDD + hi * 8;
#pragma unroll
        for (int ds = 0; ds < 4; ds++) {
            fqh[ds] = *(const bf16x8*)(qbh + ds * 16);
            fql[ds] = *(const bf16x8*)(qbl + ds * 16);
        }
    }

    // staging: wave wid owns rows [wid*8, wid*8+8) of Kh/Kl/V (3 gll/lane/tile)
    const int srow = lane >> 3, slot = lane & 7;
    const int r = wid * 8 + srow;
    const int sb = (slot ^ (r & 7)) * 16;  // pre-swizzled global source
    const size_t KSTEP = (size_t)64 * EMB * 2, VSTEP = 64 * 2;
    const char* gp[3];
    gp[0] = (const char*)kh + ((size_t)r * EMB + h * HDD) * 2 + sb;
    gp[1] = (const char*)kl + ((size_t)r * EMB + h * HDD) * 2 + sb;
    gp[2] = (const char*)vt + ((size_t)(h * HDD + r) * SEQ) * 2 + sb;
    bf16* lp[3];
#pragma unroll
    for (int i = 0; i < 3; i++) lp[i] = &lKV[0][i][wid * 512];

    f32x16 Ofr[2];
#pragma unroll
    for (int db = 0; db < 2; db++)
#pragma unroll
        for (int rg = 0; rg < 16; rg++) Ofr[db][rg] = 0.f;
    float Mr = -1e30f, Lr = 0.f;

    // prologue: stage tile 0 into buf 0
#pragma unroll
    for (int i = 0; i < 3; i++) {
        gll16(gp[i], lp[i]);
        gp[i] += (i < 2) ? KSTEP : VSTEP;
    }
    __syncthreads();

    for (int tk = 0; tk < SEQ / 64; tk++) {
        const int cur = tk & 1;
        if (tk < SEQ / 64 - 1) {
#pragma unroll
            for (int i = 0; i < 3; i++) {
                gll16(gp[i], lp[i] + (cur ^ 1) * 12288);
                gp[i] += (i < 2) ? KSTEP : VSTEP;
            }
        }
        const char* cKh = (const char*)&lKV[cur][0][0];
        const char* cKl = (const char*)&lKV[cur][1][0];
        const char* cV  = (const char*)&lKV[cur][2][0];

        // S^T = K Q^T, 3-term split, fp32 acc. A-frag row k = kb*32 + (lane&31)
        __builtin_amdgcn_s_setprio(1);
        f32x16 sfr[2];
#pragma unroll
        for (int kb = 0; kb < 2; kb++) {
            const int row = kb * 32 + qq;
            const char* rbh = cKh + row * 128;
            const char* rbl = cKl + row * 128;
            const int sw = (row & 7) << 4;
            f32x16 a;
#pragma unroll
            for (int rg = 0; rg < 16; rg++) a[rg] = 0.f;
#pragma unroll
            for (int ds = 0; ds < 4; ds++) {
                const int off = (ds * 32 + hi * 16) ^ sw;
                bf16x8 kbh_ = *(const bf16x8*)(rbh + off);
                bf16x8 kbl_ = *(const bf16x8*)(rbl + off);
                a = MFMA32(kbh_, fqh[ds], a);
                a = MFMA32(kbh_, fql[ds], a);
                a = MFMA32(kbl_, fqh[ds], a);
            }
            sfr[kb] = a;  // sfr[kb][reg]: k = kb*32 + (reg&3)+8*(reg>>2)+4*hi
        }
        __builtin_amdgcn_s_setprio(0);

        // per-tile softmax (log2 domain), ONCE per 64 keys.
        // max: nested fmaxf (max3-fusable) over 32 values + cross-half mirror
        float mA = fmaxf(fmaxf(sfr[0][0], sfr[0][1]), fmaxf(sfr[0][2], sfr[0][3]));
        float mB = fmaxf(fmaxf(sfr[0][4], sfr[0][5]), fmaxf(sfr[0][6], sfr[0][7]));
        float mC = fmaxf(fmaxf(sfr[0][8], sfr[0][9]), fmaxf(sfr[0][10], sfr[0][11]));
        float mD = fmaxf(fmaxf(sfr[0][12], sfr[0][13]), fmaxf(sfr[0][14], sfr[0][15]));
        float mE = fmaxf(fmaxf(sfr[1][0], sfr[1][1]), fmaxf(sfr[1][2], sfr[1][3]));
        float mF = fmaxf(fmaxf(sfr[1][4], sfr[1][5]), fmaxf(sfr[1][6], sfr[1][7]));
        float mG = fmaxf(fmaxf(sfr[1][8], sfr[1][9]), fmaxf(sfr[1][10], sfr[1][11]));
        float mH = fmaxf(fmaxf(sfr[1][12], sfr[1][13]), fmaxf(sfr[1][14], sfr[1][15]));
        float mx = fmaxf(fmaxf(fmaxf(mA, mB), fmaxf(mC, mD)),
                         fmaxf(fmaxf(mE, mF), fmaxf(mG, mH)));
        mx = xhalf_max(mx);

        // defer-max: skip rescale while growth <= 11.5 (= ln-domain 8)
        bool resc = !__all(mx <= Mr + 11.5f);
        float mn = resc ? fmaxf(Mr, mx) : Mr;

        // packed subtract (pk_add with -mn) into pair view, scalar exp2
        f32x2 p[16];
        f32x2 nm = (f32x2){-mn, -mn};
#pragma unroll
        for (int kb = 0; kb < 2; kb++)
#pragma unroll
            for (int i = 0; i < 8; i++)
                p[kb * 8 + i] = pk_add(
                    (f32x2){sfr[kb][2 * i], sfr[kb][2 * i + 1]}, nm);
#pragma unroll
        for (int i = 0; i < 16; i++) {
            p[i][0] = __builtin_exp2f(p[i][0]);
            p[i][1] = __builtin_exp2f(p[i][1]);
        }

        // packed sum tree: 15 pk_add + 1 add + cross-half mirror
        f32x2 s0 = pk_add(pk_add(p[0], p[1]), pk_add(p[2], p[3]));
        f32x2 s1 = pk_add(pk_add(p[4], p[5]), pk_add(p[6], p[7]));
        f32x2 s2 = pk_add(pk_add(p[8], p[9]), pk_add(p[10], p[11]));
        f32x2 s3 = pk_add(pk_add(p[12], p[13]), pk_add(p[14], p[15]));
        f32x2 sv = pk_add(pk_add(s0, s1), pk_add(s2, s3));
        float ps = sv[0] + sv[1];
        ps = xhalf_sum(ps);

        if (resc) {
            float fac = __builtin_exp2f(Mr - mn);
            Mr = mn;
            Lr = Lr * fac + ps;
            f32x2 f2 = (f32x2){fac, fac};
#pragma unroll
            for (int db = 0; db < 2; db++)
#pragma unroll
                for (int i = 0; i < 8; i++) {
                    f32x2 o = (f32x2){Ofr[db][2 * i], Ofr[db][2 * i + 1]};
                    o = pk_mul(o, f2);
                    Ofr[db][2 * i] = o[0];
                    Ofr[db][2 * i + 1] = o[1];
                }
        } else {
            Lr += ps;
        }

        // pack P to bf16 + permlane32_swap -> 4 PV B-frags, zero LDS traffic.
        bf16x8 pf[4];
#pragma unroll
        for (int sl = 0; sl < 4; sl++) {
            const int pb = sl * 4;
            unsigned w01 = pack_bf16x2(p[pb + 0][0], p[pb + 0][1]);
            unsigned w23 = pack_bf16x2(p[pb + 1][0], p[pb + 1][1]);
            unsigned w45 = pack_bf16x2(p[pb + 2][0], p[pb + 2][1]);
            unsigned w67 = pack_bf16x2(p[pb + 3][0], p[pb + 3][1]);
            u32x2 r0 = __builtin_amdgcn_permlane32_swap(w01, w45, false, false);
            u32x2 r1 = __builtin_amdgcn_permlane32_swap(w23, w67, false, false);
            u32x4 fw = {r0[0], r1[0], r0[1], r1[1]};
            bf16x8 pfv;
            __builtin_memcpy(&pfv, &fw, 16);
            pf[sl] = pfv;
        }

        // O^T += V^T P^T: A-frag row d = db*32 + (lane&31) from lV[d][k]
        __builtin_amdgcn_s_setprio(1);
#pragma unroll
        for (int sl = 0; sl < 4; sl++) {
#pragma unroll
            for (int db = 0; db < 2; db++) {
                const int vd = db * 32 + qq;
                const char* pv =
                    cV + vd * 128 + ((sl * 32 + hi * 16) ^ ((vd & 7) << 4));
                bf16x8 vf = *(const bf16x8*)pv;
                Ofr[db] = MFMA32(vf, pf[sl], Ofr[db]);
            }
        }
        __builtin_amdgcn_s_setprio(0);

        // one barrier per tile: drains prefetch (vmcnt0) + releases buf[cur]
        __syncthreads();
    }

    // epilogue: O^T[d][q] -> out[qrow][h*64 + d], d = db*32 + rg*8 + hi*4 + j
    float inv = 1.0f / Lr;
    float* orow = out + (size_t)qrow * EMB + h * HDD;
#pragma unroll
    for (int db = 0; db < 2; db++)
#pragma unroll
        for (int rg = 0; rg < 4; rg++) {
            float4 o = make_float4(Ofr[db][rg * 4 + 0] * inv,
                                   Ofr[db][rg * 4 + 1] * inv,
                                   Ofr[db][rg * 4 + 2] * inv,
                                   Ofr[db][rg * 4 + 3] * inv);
            *(float4*)(orow + db * 32 + rg * 8 + hi * 4) = o;
        }
}

// ---------------- launch ----------------
extern "C" void kernel_launch(void* const* d_in, const int* in_sizes, int n_in,
                              void* d_out, int out_size, void* d_ws, size_t ws_size,
                              hipStream_t stream) {
    const float* x = (const float*)d_in[0];
    const float* Wq = (const float*)d_in[1];
    const float* Wk = (const float*)d_in[2];
    const float* Wv = (const float*)d_in[3];
    float* out = (float*)d_out;

    char* ws = (char*)d_ws;
    size_t off = 0;
    auto alloc = [&](size_t elems) -> bf16* {
        bf16* p = (bf16*)(ws + off);
        off += elems * sizeof(bf16);
        return p;
    };
    bf16* xh = alloc((size_t)SEQ * EMB);
    bf16* xl = alloc((size_t)SEQ * EMB);
    bf16* wthq = alloc((size_t)EMB * EMB);
    bf16* wtlq = alloc((size_t)EMB * EMB);
    bf16* wthk = alloc((size_t)EMB * EMB);
    bf16* wtlk = alloc((size_t)EMB * EMB);
    bf16* wthv = alloc((size_t)EMB * EMB);
    bf16* qh = alloc((size_t)SEQ * EMB);
    bf16* ql = alloc((size_t)SEQ * EMB);
    bf16* kh = alloc((size_t)SEQ * EMB);
    bf16* kl = alloc((size_t)SEQ * EMB);
    bf16* vt = alloc((size_t)SEQ * EMB);
    (void)ws_size; (void)in_sizes; (void)n_in; (void)out_size;

    // merged prep: z=0..2 -> W transpose+split, z=3 -> x split
    prep_kernel<<<dim3(32, 32, 4), dim3(32, 8), 0, stream>>>(
        x, Wq, Wk, Wv, xh, xl, wthq, wtlq, wthk, wtlk, wthv);
    proj_qkv<<<dim3(24, 32), 256, 0, stream>>>(
        xh, xl, wthq, wtlq, wthk, wtlk, wthv, qh, ql, kh, kl, vt);
    attn_kernel<<<256, 512, 0, stream>>>(qh, ql, kh, kl, vt, out);
}

// Round 15
// 253.801 us; speedup vs baseline: 1.0341x; 1.0341x over previous
//
#include <hip/hip_runtime.h>
#include <hip/hip_bf16.h>

#define SEQ 4096
#define EMB 1024
#define NHD 16
#define HDD 64

using bf16 = __hip_bfloat16;
using bf16x8 = __attribute__((ext_vector_type(8))) short;
using f32x4  = __attribute__((ext_vector_type(4))) float;
using f32x16 = __attribute__((ext_vector_type(16))) float;
using u32x4  = __attribute__((ext_vector_type(4))) unsigned int;
using u32x2  = __attribute__((ext_vector_type(2))) unsigned int;

#define MFMA16(a, b, c) __builtin_amdgcn_mfma_f32_16x16x32_bf16((a), (b), (c), 0, 0, 0)
#define MFMA32(a, b, c) __builtin_amdgcn_mfma_f32_32x32x16_bf16((a), (b), (c), 0, 0, 0)

// logit scale: 1/sqrt(64) * log2(e), folded into Q projection
#define QSCALE 0.1803368801111204f

__device__ __forceinline__ float b2f(bf16 b) { return __bfloat162float(b); }

__device__ __forceinline__ void gll16(const void* g, void* l) {
    __builtin_amdgcn_global_load_lds(
        (const __attribute__((address_space(1))) unsigned int*)g,
        (__attribute__((address_space(3))) unsigned int*)l, 16, 0, 0);
}

__device__ __forceinline__ unsigned pack_bf16x2(float a, float b) {
    __hip_bfloat162 p = __float22bfloat162_rn(make_float2(a, b));
    unsigned w;
    __builtin_memcpy(&w, &p, 4);
    return w;
}

// cross-half (lane i <-> i+32) reduce via permlane32_swap mirror trick:
// swap(u,u) returns {lo-half view, hi-half view}; combining them reduces
// across the half-wave split with pure VALU (no ds_bpermute / lgkm wait).
__device__ __forceinline__ float xhalf_max(float x) {
    unsigned u;
    __builtin_memcpy(&u, &x, 4);
    u32x2 r = __builtin_amdgcn_permlane32_swap(u, u, false, false);
    unsigned u0 = r[0], u1 = r[1];
    float a, b;
    __builtin_memcpy(&a, &u0, 4);
    __builtin_memcpy(&b, &u1, 4);
    return fmaxf(a, b);
}
__device__ __forceinline__ float xhalf_sum(float x) {
    unsigned u;
    __builtin_memcpy(&u, &x, 4);
    u32x2 r = __builtin_amdgcn_permlane32_swap(u, u, false, false);
    unsigned u0 = r[0], u1 = r[1];
    float a, b;
    __builtin_memcpy(&a, &u0, 4);
    __builtin_memcpy(&b, &u1, 4);
    return a + b;
}

// ---------------- prep: split f32 -> hi/lo bf16 ----------------
__global__ void split_kernel(const float* __restrict__ src, bf16* __restrict__ hi,
                             bf16* __restrict__ lo, int n4) {
    int i = blockIdx.x * blockDim.x + threadIdx.x;
    if (i >= n4) return;
    float4 v = ((const float4*)src)[i];
    float vv[4] = {v.x, v.y, v.z, v.w};
#pragma unroll
    for (int j = 0; j < 4; j++) {
        bf16 h = __float2bfloat16(vv[j]);
        hi[i * 4 + j] = h;
        lo[i * 4 + j] = __float2bfloat16(vv[j] - b2f(h));
    }
}

// ---------------- prep: W[k][n] f32 -> Wt[n][k] hi/lo bf16 (all 3 W) ------
__global__ void wtrans_kernel(const float* __restrict__ Wq, const float* __restrict__ Wk,
                              const float* __restrict__ Wv,
                              bf16* __restrict__ thq, bf16* __restrict__ tlq,
                              bf16* __restrict__ thk, bf16* __restrict__ tlk,
                              bf16* __restrict__ thv, bf16* __restrict__ tlv) {
    __shared__ float tile[32][33];
    const float* W;
    bf16 *wth, *wtl;
    if (blockIdx.z == 0) { W = Wq; wth = thq; wtl = tlq; }
    else if (blockIdx.z == 1) { W = Wk; wth = thk; wtl = tlk; }
    else { W = Wv; wth = thv; wtl = tlv; }
    int n0 = blockIdx.x * 32, k0 = blockIdx.y * 32;
    int tx = threadIdx.x, ty = threadIdx.y;
    for (int r = ty; r < 32; r += 8)
        tile[r][tx] = W[(k0 + r) * EMB + n0 + tx];
    __syncthreads();
    for (int r = ty; r < 32; r += 8) {
        float v = tile[tx][r];  // = W[k0+tx][n0+r]
        bf16 h = __float2bfloat16(v);
        wth[(n0 + r) * EMB + k0 + tx] = h;
        wtl[(n0 + r) * EMB + k0 + tx] = __float2bfloat16(v - b2f(h));
    }
}

// ---------------- fused QKV projection GEMM ----------------
template <int NTERMS>
__device__ __forceinline__ void proj_loop(
    const bf16* __restrict__ Ah, const bf16* __restrict__ Al,
    const bf16* __restrict__ Bth, const bf16* __restrict__ Btl,
    bf16* lAh, bf16* lAl, bf16* lBh, bf16* lBl,
    int m0, int n0, int t, f32x4 (&acc)[4][4]) {
    const int wid = t >> 6, lane = t & 63, lr = lane & 15, lg = lane >> 4;
    const int wr = (wid >> 1) * 64, wc = (wid & 1) * 64;
    for (int k0 = 0; k0 < EMB; k0 += 32) {
#pragma unroll
        for (int c = t; c < 512; c += 256) {
            int row = c >> 2, slot = c & 3;
            *(uint4*)&lAh[row * 40 + slot * 8] =
                *(const uint4*)&Ah[(m0 + row) * EMB + k0 + slot * 8];
            *(uint4*)&lBh[row * 40 + slot * 8] =
                *(const uint4*)&Bth[(n0 + row) * EMB + k0 + slot * 8];
            if constexpr (NTERMS == 3) {
                *(uint4*)&lAl[row * 40 + slot * 8] =
                    *(const uint4*)&Al[(m0 + row) * EMB + k0 + slot * 8];
                *(uint4*)&lBl[row * 40 + slot * 8] =
                    *(const uint4*)&Btl[(n0 + row) * EMB + k0 + slot * 8];
            }
        }
        __syncthreads();
        bf16x8 fah[4], fbh[4], fal[4], fbl[4];
#pragma unroll
        for (int i = 0; i < 4; i++) {
            fah[i] = *(const bf16x8*)&lAh[(wr + i * 16 + lr) * 40 + lg * 8];
            fbh[i] = *(const bf16x8*)&lBh[(wc + i * 16 + lr) * 40 + lg * 8];
            if constexpr (NTERMS == 3) {
                fal[i] = *(const bf16x8*)&lAl[(wr + i * 16 + lr) * 40 + lg * 8];
                fbl[i] = *(const bf16x8*)&lBl[(wc + i * 16 + lr) * 40 + lg * 8];
            }
        }
#pragma unroll
        for (int i = 0; i < 4; i++)
#pragma unroll
            for (int j = 0; j < 4; j++) {
                acc[i][j] = MFMA16(fah[i], fbh[j], acc[i][j]);
                if constexpr (NTERMS == 3) {
                    acc[i][j] = MFMA16(fah[i], fbl[j], acc[i][j]);
                    acc[i][j] = MFMA16(fal[i], fbh[j], acc[i][j]);
                }
            }
        __syncthreads();
    }
}

// grid (24, 32): x covers 3*EMB columns (8 tiles each for Q,K,V), y covers SEQ rows
__global__ __launch_bounds__(256) void proj_qkv(
    const bf16* __restrict__ xh, const bf16* __restrict__ xl,
    const bf16* __restrict__ thq, const bf16* __restrict__ tlq,
    const bf16* __restrict__ thk, const bf16* __restrict__ tlk,
    const bf16* __restrict__ thv,
    bf16* __restrict__ qh, bf16* __restrict__ ql,
    bf16* __restrict__ kh, bf16* __restrict__ kl, bf16* __restrict__ vt) {
    __shared__ __align__(16) bf16 lAh[128 * 40];
    __shared__ __align__(16) bf16 lAl[128 * 40];
    __shared__ __align__(16) bf16 lBh[128 * 40];
    __shared__ __align__(16) bf16 lBl[128 * 40];
    const int t = threadIdx.x;
    const int m0 = blockIdx.y * 128;
    const int which = blockIdx.x >> 3;
    const int n0 = (blockIdx.x & 7) * 128;

    f32x4 acc[4][4];
#pragma unroll
    for (int i = 0; i < 4; i++)
#pragma unroll
        for (int j = 0; j < 4; j++) acc[i][j] = (f32x4){0.f, 0.f, 0.f, 0.f};

    if (which == 0)
        proj_loop<3>(xh, xl, thq, tlq, lAh, lAl, lBh, lBl, m0, n0, t, acc);
    else if (which == 1)
        proj_loop<3>(xh, xl, thk, tlk, lAh, lAl, lBh, lBl, m0, n0, t, acc);
    else
        proj_loop<1>(xh, xl, thv, nullptr, lAh, lAl, lBh, lBl, m0, n0, t, acc);

    const int wid = t >> 6, lane = t & 63, lr = lane & 15, lg = lane >> 4;
    const int wr = (wid >> 1) * 64, wc = (wid & 1) * 64;

    if (which == 2) {
        // V: write directly transposed vt[(h*64+d)*SEQ + m], 8B packed stores
#pragma unroll
        for (int i = 0; i < 4; i++)
#pragma unroll
            for (int j = 0; j < 4; j++) {
                int n = n0 + wc + j * 16 + lr;       // column in V = h*64 + d
                int m = m0 + wr + i * 16 + lg * 4;   // 4 consecutive seq rows
                uint2 w;
                w.x = pack_bf16x2(acc[i][j][0], acc[i][j][1]);
                w.y = pack_bf16x2(acc[i][j][2], acc[i][j][3]);
                *(uint2*)&vt[(size_t)n * SEQ + m] = w;
            }
    } else {
        float scale = (which == 0) ? QSCALE : 1.0f;
        bf16* Chi = (which == 0) ? qh : kh;
        bf16* Clo = (which == 0) ? ql : kl;
#pragma unroll
        for (int i = 0; i < 4; i++)
#pragma unroll
            for (int j = 0; j < 4; j++)
#pragma unroll
                for (int q = 0; q < 4; q++) {
                    float cv = acc[i][j][q] * scale;
                    int m = m0 + wr + i * 16 + lg * 4 + q;
                    int n = n0 + wc + j * 16 + lr;
                    bf16 hv = __float2bfloat16(cv);
                    Chi[m * EMB + n] = hv;
                    Clo[m * EMB + n] = __float2bfloat16(cv - b2f(hv));
                }
    }
}

// ---------------- fused flash attention v11: round-7 exact + tree balance --
// Identical to round-7's best (v4: 32x32 MFMA, QBLK=256, 8 waves, dbuf K/V,
// in-register P, grid 256, XCD swizzle) EXCEPT: (a) balanced max/sum trees
// (plain C, depth 5, max3-fusable) replacing 31-deep serial chains;
// (b) cross-half reduces via permlane32_swap builtin mirror (VALU) instead
// of __shfl_xor (ds_bpermute + lgkm wait in critical path). No inline asm.
__global__ __launch_bounds__(512, 2) void attn_kernel(
    const bf16* __restrict__ qh, const bf16* __restrict__ ql,
    const bf16* __restrict__ kh, const bf16* __restrict__ kl,
    const bf16* __restrict__ vt, float* __restrict__ out) {
    __shared__ __align__(16) bf16 lKV[2][3][64 * 64];  // 48 KB
    const int t = threadIdx.x;
    // XCD-bijective swizzle (256 % 8 == 0): 32 consecutive swz per XCD = 2 heads
    const int swz = (blockIdx.x & 7) * 32 + (blockIdx.x >> 3);
    const int h = swz >> 4;
    const int q0 = (swz & 15) * 256;
    const int wid = t >> 6, lane = t & 63;
    const int qq = lane & 31, hi = lane >> 5;
    const int qrow = q0 + wid * 32 + qq;

    // Q fragments (B-operand): col q = lane&31, k(d) = ds*16 + hi*8 + i
    bf16x8 fqh[4], fql[4];
    {
        const bf16* qbh = qh + (size_t)qrow * EMB + h * HDD + hi * 8;
        const bf16* qbl = ql + (size_t)qrow * EMB + h * HDD + hi * 8;
#pragma unroll
        for (int ds = 0; ds < 4; ds++) {
            fqh[ds] = *(const bf16x8*)(qbh + ds * 16);
            fql[ds] = *(const bf16x8*)(qbl + ds * 16);
        }
    }

    // staging: wave wid owns rows [wid*8, wid*8+8) of Kh/Kl/V (3 gll/lane/tile)
    const int srow = lane >> 3, slot = lane & 7;
    const int r = wid * 8 + srow;
    const int sb = (slot ^ (r & 7)) * 16;  // pre-swizzled global source
    const char* gp[3];
    gp[0] = (const char*)kh + ((size_t)r * EMB + h * HDD) * 2 + sb;
    gp[1] = (const char*)kl + ((size_t)r * EMB + h * HDD) * 2 + sb;
    gp[2] = (const char*)vt + ((size_t)(h * HDD + r) * SEQ) * 2 + sb;
    bf16* lp[3];
#pragma unroll
    for (int i = 0; i < 3; i++) lp[i] = &lKV[0][i][wid * 512];

    f32x16 Ofr[2];
#pragma unroll
    for (int db = 0; db < 2; db++)
#pragma unroll
        for (int rg = 0; rg < 16; rg++) Ofr[db][rg] = 0.f;
    float Mr = -1e30f, Lr = 0.f;

    // prologue: stage tile 0 into buf 0
#pragma unroll
    for (int i = 0; i < 3; i++) {
        gll16(gp[i], lp[i]);
        gp[i] += (i < 2) ? (size_t)(64 * EMB * 2) : (size_t)(64 * 2);
    }
    __syncthreads();

    for (int tk = 0; tk < SEQ / 64; tk++) {
        const int cur = tk & 1;
        if (tk < SEQ / 64 - 1) {
#pragma unroll
            for (int i = 0; i < 3; i++) {
                gll16(gp[i], lp[i] + (cur ^ 1) * 12288);
                gp[i] += (i < 2) ? (size_t)(64 * EMB * 2) : (size_t)(64 * 2);
            }
        }
        const char* cKh = (const char*)&lKV[cur][0][0];
        const char* cKl = (const char*)&lKV[cur][1][0];
        const char* cV  = (const char*)&lKV[cur][2][0];

        // S^T = K Q^T, 3-term split, fp32 acc. A-frag row k = kb*32 + (lane&31)
        __builtin_amdgcn_s_setprio(1);
        f32x16 sfr[2];
#pragma unroll
        for (int kb = 0; kb < 2; kb++) {
            const int row = kb * 32 + qq;
            const char* rbh = cKh + row * 128;
            const char* rbl = cKl + row * 128;
            const int sw = (row & 7) << 4;
            f32x16 a;
#pragma unroll
            for (int rg = 0; rg < 16; rg++) a[rg] = 0.f;
#pragma unroll
            for (int ds = 0; ds < 4; ds++) {
                const int off = (ds * 32 + hi * 16) ^ sw;
                bf16x8 kbh_ = *(const bf16x8*)(rbh + off);
                bf16x8 kbl_ = *(const bf16x8*)(rbl + off);
                a = MFMA32(kbh_, fqh[ds], a);
                a = MFMA32(kbh_, fql[ds], a);
                a = MFMA32(kbl_, fqh[ds], a);
            }
            sfr[kb] = a;  // sfr[kb][reg]: k = kb*32 + (reg&3)+8*(reg>>2)+4*hi
        }
        __builtin_amdgcn_s_setprio(0);

        // online softmax (log2 domain); balanced max tree (depth 5)
        float mA = fmaxf(fmaxf(sfr[0][0], sfr[0][1]), fmaxf(sfr[0][2], sfr[0][3]));
        float mB = fmaxf(fmaxf(sfr[0][4], sfr[0][5]), fmaxf(sfr[0][6], sfr[0][7]));
        float mC = fmaxf(fmaxf(sfr[0][8], sfr[0][9]), fmaxf(sfr[0][10], sfr[0][11]));
        float mD = fmaxf(fmaxf(sfr[0][12], sfr[0][13]), fmaxf(sfr[0][14], sfr[0][15]));
        float mE = fmaxf(fmaxf(sfr[1][0], sfr[1][1]), fmaxf(sfr[1][2], sfr[1][3]));
        float mF = fmaxf(fmaxf(sfr[1][4], sfr[1][5]), fmaxf(sfr[1][6], sfr[1][7]));
        float mG = fmaxf(fmaxf(sfr[1][8], sfr[1][9]), fmaxf(sfr[1][10], sfr[1][11]));
        float mH = fmaxf(fmaxf(sfr[1][12], sfr[1][13]), fmaxf(sfr[1][14], sfr[1][15]));
        float mx = fmaxf(fmaxf(fmaxf(mA, mB), fmaxf(mC, mD)),
                         fmaxf(fmaxf(mE, mF), fmaxf(mG, mH)));
        mx = xhalf_max(mx);

        // defer-max (T13): skip rescale while growth <= 11.5 (= ln-domain 8)
        bool resc = !__all(mx <= Mr + 11.5f);
        float mn = resc ? fmaxf(Mr, mx) : Mr;
#pragma unroll
        for (int kb = 0; kb < 2; kb++)
#pragma unroll
            for (int rg = 0; rg < 16; rg++)
                sfr[kb][rg] = __builtin_exp2f(sfr[kb][rg] - mn);
        // balanced sum tree (depth 5)
        float s16[16];
#pragma unroll
        for (int i = 0; i < 16; i++) s16[i] = sfr[0][i] + sfr[1][i];
        float s8[8];
#pragma unroll
        for (int i = 0; i < 8; i++) s8[i] = s16[i] + s16[i + 8];
        float ps = ((s8[0] + s8[1]) + (s8[2] + s8[3])) +
                   ((s8[4] + s8[5]) + (s8[6] + s8[7]));
        ps = xhalf_sum(ps);
        if (resc) {
            float fac = __builtin_exp2f(Mr - mn);
            Mr = mn;
            Lr = Lr * fac + ps;
#pragma unroll
            for (int db = 0; db < 2; db++)
#pragma unroll
                for (int rg = 0; rg < 16; rg++) Ofr[db][rg] *= fac;
        } else {
            Lr += ps;
        }

        // pack P to bf16 + permlane32_swap -> PV B-frags, zero LDS traffic.
        bf16x8 pf[4];
#pragma unroll
        for (int sl = 0; sl < 4; sl++) {
            const int kb = sl >> 1, s8i = (sl & 1) * 8;
            unsigned w01 = pack_bf16x2(sfr[kb][s8i + 0], sfr[kb][s8i + 1]);
            unsigned w23 = pack_bf16x2(sfr[kb][s8i + 2], sfr[kb][s8i + 3]);
            unsigned w45 = pack_bf16x2(sfr[kb][s8i + 4], sfr[kb][s8i + 5]);
            unsigned w67 = pack_bf16x2(sfr[kb][s8i + 6], sfr[kb][s8i + 7]);
            u32x2 r0 = __builtin_amdgcn_permlane32_swap(w01, w45, false, false);
            u32x2 r1 = __builtin_amdgcn_permlane32_swap(w23, w67, false, false);
            u32x4 fw = {r0[0], r1[0], r0[1], r1[1]};
            bf16x8 pfv;
            __builtin_memcpy(&pfv, &fw, 16);
            pf[sl] = pfv;
        }

        // O^T += V^T P^T: A-frag row d = db*32 + (lane&31) from lV[d][k]
        __builtin_amdgcn_s_setprio(1);
#pragma unroll
        for (int sl = 0; sl < 4; sl++) {
#pragma unroll
            for (int db = 0; db < 2; db++) {
                const int vd = db * 32 + qq;
                const char* pv =
                    cV + vd * 128 + ((sl * 32 + hi * 16) ^ ((vd & 7) << 4));
                bf16x8 vf = *(const bf16x8*)pv;
                Ofr[db] = MFMA32(vf, pf[sl], Ofr[db]);
            }
        }
        __builtin_amdgcn_s_setprio(0);

        // one barrier per tile: drains prefetch (vmcnt0) + releases buf[cur]
        __syncthreads();
    }

    // epilogue: O^T[d][q] -> out[qrow][h*64 + d], d = db*32 + rg*8 + hi*4 + j
    float inv = 1.0f / Lr;
    float* orow = out + (size_t)qrow * EMB + h * HDD;
#pragma unroll
    for (int db = 0; db < 2; db++)
#pragma unroll
        for (int rg = 0; rg < 4; rg++) {
            float4 o = make_float4(Ofr[db][rg * 4 + 0] * inv,
                                   Ofr[db][rg * 4 + 1] * inv,
                                   Ofr[db][rg * 4 + 2] * inv,
                                   Ofr[db][rg * 4 + 3] * inv);
            *(float4*)(orow + db * 32 + rg * 8 + hi * 4) = o;
        }
}

// ---------------- launch ----------------
extern "C" void kernel_launch(void* const* d_in, const int* in_sizes, int n_in,
                              void* d_out, int out_size, void* d_ws, size_t ws_size,
                              hipStream_t stream) {
    const float* x = (const float*)d_in[0];
    const float* Wq = (const float*)d_in[1];
    const float* Wk = (const float*)d_in[2];
    const float* Wv = (const float*)d_in[3];
    float* out = (float*)d_out;

    char* ws = (char*)d_ws;
    size_t off = 0;
    auto alloc = [&](size_t elems) -> bf16* {
        bf16* p = (bf16*)(ws + off);
        off += elems * sizeof(bf16);
        return p;
    };
    bf16* xh = alloc((size_t)SEQ * EMB);
    bf16* xl = alloc((size_t)SEQ * EMB);
    bf16* wthq = alloc((size_t)EMB * EMB);
    bf16* wtlq = alloc((size_t)EMB * EMB);
    bf16* wthk = alloc((size_t)EMB * EMB);
    bf16* wtlk = alloc((size_t)EMB * EMB);
    bf16* wthv = alloc((size_t)EMB * EMB);
    bf16* wtlv = alloc((size_t)EMB * EMB);
    bf16* qh = alloc((size_t)SEQ * EMB);
    bf16* ql = alloc((size_t)SEQ * EMB);
    bf16* kh = alloc((size_t)SEQ * EMB);
    bf16* kl = alloc((size_t)SEQ * EMB);
    bf16* vt = alloc((size_t)SEQ * EMB);
    (void)ws_size; (void)in_sizes; (void)n_in; (void)out_size;

    split_kernel<<<(SEQ * EMB / 4 + 255) / 256, 256, 0, stream>>>(x, xh, xl, SEQ * EMB / 4);
    wtrans_kernel<<<dim3(32, 32, 3), dim3(32, 8), 0, stream>>>(
        Wq, Wk, Wv, wthq, wtlq, wthk, wtlk, wthv, wtlv);
    proj_qkv<<<dim3(24, 32), 256, 0, stream>>>(
        xh, xl, wthq, wtlq, wthk, wtlk, wthv, qh, ql, kh, kl, vt);
    attn_kernel<<<256, 512, 0, stream>>>(qh, ql, kh, kl, vt, out);
}